// Round 19
// baseline (162.922 us; speedup 1.0000x reference)
//
#include <hip/hip_runtime.h>
#include <hip/hip_bf16.h>

// VanillaVectorQuantizer: N=131072 pos (B=32,H=64,W=64), D=64, K=512.
// enc [B,D,H,W]: (b,d,p) at b*D*HW + d*HW + p.
//
// Architecture (r13-r18-proven, absmax==0): MFMA screen + bounded exact
// rescore. r19 = WAVE-AUTONOMOUS variant: after one staging barrier, each
// wave owns 16 positions x all 512 k -> per-row global min computed fully
// in-wave (fmin accumulation over 8 k-ranges + DPP butterfly); candidates
// collected into wave-owned LDS rows; rescore+output same-wave (LDS ops
// in-order within a wave) -> NO further barriers. Attacks the ~74us plateau
// shared by r14/r15/r17/r18 (4 structures, all pipes <36%): barrier-locked
// phase chains exposing memory latency to whole blocks.
//  screen: dd'_k = fl(sqe_k - 2*acc_k), acc = bf16 MFMA (fp32 accum).
//  bound:  B = 0.012*sqrt(sqx*maxsqe) + 3e-4  (r14-r18-verified).
//  capture: cand = {k: dd' <= gmin + 2B} -> true argmin + all exact ties.
//  n==1 fast path: unique candidate == provable argmin, no rescore.
//  rescore: EXACT numpy chain (bitwise, r2-r18): M ascending-d fp32 FMA;
//    sq_x pairwise tree; dist fl(fl(sqx-fl(2M))+sqe); u64 (distbits,k)
//    atomicMin == first-index tie-break. Overflow(>16) -> full 512 rescan.
// MFMA frags (r13-r18-verified): A = xbf[(row)*72 + s*32 + 8*hi];
// B = cbT[kg*64 + s*32 + 8*hi], kg = kr*64 + kt*16 + m; C/D row=4*hi+j,
// col=m (m=lane&15, hi=lane>>4). B-frags now read from GLOBAL cbT (L2-hot).

#pragma clang fp contract(off)

#define D 64
#define Kc 512
#define HW 4096
#define Np 131072
#define POSB 128
#define CAP 16

typedef __attribute__((ext_vector_type(8))) short bf16x8;
typedef __attribute__((ext_vector_type(4))) float f32x4;

static __device__ __forceinline__ unsigned short f2bf(float f) {
    __hip_bfloat16 h = __float2bfloat16(f);  // RN-even (bound covers it)
    return *reinterpret_cast<unsigned short*>(&h);
}

// DPP value-move (VALU pipe; r18-HW-verified encodings).
// 0xB1 = quad_perm(1,0,3,2) == xor1; 0x4E = quad_perm(2,3,0,1) == xor2;
// 0x124 = row_ror:4; 0x128 = row_ror:8 (row = 16 lanes).
template <int CTRL>
static __device__ __forceinline__ float dpp_mov(float x) {
    return __int_as_float(__builtin_amdgcn_update_dpp(
        __float_as_int(x), __float_as_int(x), CTRL, 0xF, 0xF, false));
}
static __device__ __forceinline__ float dpp_rowmin16(float x) {
    x = fminf(x, dpp_mov<0xB1>(x));
    x = fminf(x, dpp_mov<0x4E>(x));
    x = fminf(x, dpp_mov<0x124>(x));
    x = fminf(x, dpp_mov<0x128>(x));
    return x;  // all 16 lanes hold the row min
}

// Prep: exact sqe chain, max(sqe), cbT bf16 [512][64] (k-major).
__global__ __launch_bounds__(512) void vq_prep(
    const float* __restrict__ cb, float* __restrict__ sqe,
    float* __restrict__ maxsqe, unsigned short* __restrict__ cbT) {
    __shared__ float red[512];
    const int k = threadIdx.x;
    float s;
    unsigned pk[32];
    {
        const float v0 = cb[k], v1 = cb[Kc + k];
        s = v0 * v0;
        const float sq1 = v1 * v1;
        s = s + sq1;
        pk[0] = (unsigned)f2bf(v0) | ((unsigned)f2bf(v1) << 16);
    }
#pragma unroll
    for (int i = 1; i < 32; ++i) {
        const float v0 = cb[(2 * i) * Kc + k], v1 = cb[(2 * i + 1) * Kc + k];
        const float sq0 = v0 * v0;
        s = s + sq0;
        const float sq1 = v1 * v1;
        s = s + sq1;
        pk[i] = (unsigned)f2bf(v0) | ((unsigned)f2bf(v1) << 16);
    }
    sqe[k] = s;
    unsigned* crow = (unsigned*)(cbT + k * 64);
#pragma unroll
    for (int i = 0; i < 32; ++i) crow[i] = pk[i];
    red[k] = s;
    __syncthreads();
    for (int off = 256; off > 0; off >>= 1) {
        if (k < off) red[k] = fmaxf(red[k], red[k + off]);
        __syncthreads();
    }
    if (k == 0) maxsqe[0] = red[0];
}

__global__ __launch_bounds__(512) void vq_mfma7(
    const float* __restrict__ enc, const float* __restrict__ cb,
    const float* __restrict__ sqe, const float* __restrict__ maxsqe_p,
    const unsigned short* __restrict__ cbT, float* __restrict__ out) {
    __shared__ unsigned short xbf[POSB * 72];    // 18432 B, stride 144B
    __shared__ float sqx[POSB];                  //   512 B
    __shared__ float thrB[POSB];                 //   512 B (= 2*Bnd)
    __shared__ unsigned cnt[POSB];               //   512 B
    __shared__ unsigned short list[POSB * CAP];  //  4096 B
    __shared__ unsigned long long rmin[POSB];    //  1024 B (~25 KB)

    const int tid = threadIdx.x;
    const int w = tid >> 6;
    const int lane = tid & 63;
    const int m = lane & 15, hi = lane >> 4;
    const int p0 = blockIdx.x * POSB;  // 128 | 4096: block within one b
    const int b = p0 >> 12;
    const int r0 = p0 & (HW - 1);
    const float* eb = enc + (size_t)b * (D * HW) + r0;

    // ---- Stage (r16-r18-verified): thread owns (p = tid>>2, h = tid&3):
    // stride-8 pairwise accumulators; quad-DPP tree completes sx bitwise. ----
    {
        const int p = tid >> 2, h = tid & 3;
        const float* ebp = eb + p;
        float pa, pb2;
        {
            const int d = 2 * h;
            const float v0 = ebp[(size_t)d * HW], v1 = ebp[(size_t)(d + 1) * HW];
            pa = v0 * v0;
            pb2 = v1 * v1;
            *reinterpret_cast<unsigned*>(
                reinterpret_cast<char*>(xbf) + p * 144 + 4 * h) =
                (unsigned)f2bf(v0) | ((unsigned)f2bf(v1) << 16);
        }
#pragma unroll
        for (int i = 1; i < 8; ++i) {
            const int d = 8 * i + 2 * h;
            const float v0 = ebp[(size_t)d * HW], v1 = ebp[(size_t)(d + 1) * HW];
            const float s0 = v0 * v0;  // rounded square
            pa = pa + s0;              // rounded add (stride-8 acc 2h)
            const float s1 = v1 * v1;
            pb2 = pb2 + s1;            // (stride-8 acc 2h+1)
            *reinterpret_cast<unsigned*>(
                reinterpret_cast<char*>(xbf) + p * 144 + 16 * i + 4 * h) =
                (unsigned)f2bf(v0) | ((unsigned)f2bf(v1) << 16);
        }
        const float node = pa + pb2;             // n_h
        const float o1 = dpp_mov<0xB1>(node);    // lane^1 partner
        const float t = node + o1;               // n0+n1 / n2+n3
        const float o2 = dpp_mov<0x4E>(t);       // lane^2 partner
        const float sx = t + o2;                 // full tree
        if (h == 0) {
            sqx[p] = sx;
            thrB[p] = 2.0f * (0.012f * sqrtf(sx * maxsqe_p[0]) + 3e-4f);
        }
    }
    if (tid < POSB) {
        cnt[tid] = 0;
        rmin[tid] = ~0ULL;
    }
    __syncthreads();  // THE ONLY BARRIER

    // ---- Wave w owns rows rowb..rowb+15 (positions) for ALL 512 k ----
    const int rowb = w * 16;
    const bf16x8 A0 = *reinterpret_cast<const bf16x8*>(
        &xbf[(rowb + m) * 72 + 8 * hi]);
    const bf16x8 A1 = *reinterpret_cast<const bf16x8*>(
        &xbf[(rowb + m) * 72 + 32 + 8 * hi]);

    // Sweep 1: global (over 512 k) per-row min, fully in-wave.
    float mn0 = 3.4e38f, mn1 = 3.4e38f, mn2 = 3.4e38f, mn3 = 3.4e38f;
#pragma unroll
    for (int kr = 0; kr < 8; ++kr) {
        bf16x8 Bf[4][2];
        float se[4];
#pragma unroll
        for (int kt = 0; kt < 4; ++kt) {
            const int kg = kr * 64 + kt * 16 + m;
#pragma unroll
            for (int s = 0; s < 2; ++s)
                Bf[kt][s] = *reinterpret_cast<const bf16x8*>(
                    &cbT[kg * 64 + s * 32 + 8 * hi]);
            se[kt] = sqe[kg];
        }
        f32x4 acc[4] = {};
#pragma unroll
        for (int kt = 0; kt < 4; ++kt)
            acc[kt] = __builtin_amdgcn_mfma_f32_16x16x32_bf16(
                A0, Bf[kt][0], acc[kt], 0, 0, 0);
#pragma unroll
        for (int kt = 0; kt < 4; ++kt)
            acc[kt] = __builtin_amdgcn_mfma_f32_16x16x32_bf16(
                A1, Bf[kt][1], acc[kt], 0, 0, 0);
#pragma unroll
        for (int kt = 0; kt < 4; ++kt) {
            mn0 = fminf(mn0, fmaf(-2.f, acc[kt][0], se[kt]));
            mn1 = fminf(mn1, fmaf(-2.f, acc[kt][1], se[kt]));
            mn2 = fminf(mn2, fmaf(-2.f, acc[kt][2], se[kt]));
            mn3 = fminf(mn3, fmaf(-2.f, acc[kt][3], se[kt]));
        }
    }
    mn0 = dpp_rowmin16(mn0);  // = gmin for row rowb+4*hi+0
    mn1 = dpp_rowmin16(mn1);
    mn2 = dpp_rowmin16(mn2);
    mn3 = dpp_rowmin16(mn3);
    const float win0 = mn0 + thrB[rowb + 4 * hi + 0];
    const float win1 = mn1 + thrB[rowb + 4 * hi + 1];
    const float win2 = mn2 + thrB[rowb + 4 * hi + 2];
    const float win3 = mn3 + thrB[rowb + 4 * hi + 3];

    // Sweep 2: recompute dd' (deterministic), collect candidates into this
    // wave's own rows (no other wave touches them -> no barrier needed).
#pragma unroll
    for (int kr = 0; kr < 8; ++kr) {
        bf16x8 Bf[4][2];
        float se[4];
#pragma unroll
        for (int kt = 0; kt < 4; ++kt) {
            const int kg = kr * 64 + kt * 16 + m;
#pragma unroll
            for (int s = 0; s < 2; ++s)
                Bf[kt][s] = *reinterpret_cast<const bf16x8*>(
                    &cbT[kg * 64 + s * 32 + 8 * hi]);
            se[kt] = sqe[kg];
        }
        f32x4 acc[4] = {};
#pragma unroll
        for (int kt = 0; kt < 4; ++kt)
            acc[kt] = __builtin_amdgcn_mfma_f32_16x16x32_bf16(
                A0, Bf[kt][0], acc[kt], 0, 0, 0);
#pragma unroll
        for (int kt = 0; kt < 4; ++kt)
            acc[kt] = __builtin_amdgcn_mfma_f32_16x16x32_bf16(
                A1, Bf[kt][1], acc[kt], 0, 0, 0);
#pragma unroll
        for (int kt = 0; kt < 4; ++kt) {
            const unsigned kg = kr * 64 + kt * 16 + m;
            const float dd0 = fmaf(-2.f, acc[kt][0], se[kt]);
            const float dd1 = fmaf(-2.f, acc[kt][1], se[kt]);
            const float dd2 = fmaf(-2.f, acc[kt][2], se[kt]);
            const float dd3 = fmaf(-2.f, acc[kt][3], se[kt]);
            if (dd0 <= win0) {
                const unsigned idx = atomicAdd(&cnt[rowb + 4 * hi + 0], 1u);
                if (idx < CAP) list[(rowb + 4 * hi + 0) * CAP + idx] = (unsigned short)kg;
            }
            if (dd1 <= win1) {
                const unsigned idx = atomicAdd(&cnt[rowb + 4 * hi + 1], 1u);
                if (idx < CAP) list[(rowb + 4 * hi + 1) * CAP + idx] = (unsigned short)kg;
            }
            if (dd2 <= win2) {
                const unsigned idx = atomicAdd(&cnt[rowb + 4 * hi + 2], 1u);
                if (idx < CAP) list[(rowb + 4 * hi + 2) * CAP + idx] = (unsigned short)kg;
            }
            if (dd3 <= win3) {
                const unsigned idx = atomicAdd(&cnt[rowb + 4 * hi + 3], 1u);
                if (idx < CAP) list[(rowb + 4 * hi + 3) * CAP + idx] = (unsigned short)kg;
            }
        }
    }

    // ---- Exact rescore of this wave's 16 rows; 4 lanes per pos.
    // Same-wave LDS ops are in program order -> no barrier. ----
    {
        const int ploc = lane & 15, sub = lane >> 4;
        const int p = rowb + ploc;
        const unsigned n = cnt[p];
        if (n == 1) {
            if (sub == 0) rmin[p] = (unsigned long long)list[p * CAP];
        } else if (n <= CAP) {
            const float sx = sqx[p];
            unsigned long long mloc = ~0ULL;
            for (unsigned c = sub; c < n; c += 4) {
                const int k = list[p * CAP + c];
                float M = 0.f;
#pragma unroll 8
                for (int d = 0; d < D; ++d)
                    M = fmaf(eb[(size_t)d * HW + p], cb[d * Kc + k], M);
                const float m2 = 2.0f * M;
                const float tmp = sx - m2;
                const float dd = tmp + sqe[k];
                const unsigned long long pk =
                    ((unsigned long long)__float_as_uint(dd) << 32) | (unsigned)k;
                if (pk < mloc) mloc = pk;
            }
            if (mloc != ~0ULL) atomicMin(&rmin[p], mloc);
        } else {  // overflow: full exact rescan (practically never; airtight)
            const float sx = sqx[p];
            unsigned long long mloc = ~0ULL;
            for (unsigned k = sub; k < (unsigned)Kc; k += 4) {
                float M = 0.f;
#pragma unroll 8
                for (int d = 0; d < D; ++d)
                    M = fmaf(eb[(size_t)d * HW + p], cb[d * Kc + k], M);
                const float m2 = 2.0f * M;
                const float tmp = sx - m2;
                const float dd = tmp + sqe[k];
                const unsigned long long pk =
                    ((unsigned long long)__float_as_uint(dd) << 32) | k;
                if (pk < mloc) mloc = pk;
            }
            atomicMin(&rmin[p], mloc);
        }
    }

    // ---- Output this wave's 16 positions: lane (ploc, dgrp) writes 16
    // d-planes; stores form 4x64B segments per instruction. ----
    {
        const int ploc = lane & 15, dgrp = lane >> 4;
        const int kf = (int)(rmin[rowb + ploc] & 0xffffffffu);
        float* ob = out + (size_t)b * (D * HW) + r0 + rowb + ploc;
#pragma unroll
        for (int dd2 = 0; dd2 < 16; ++dd2) {
            const int d = dgrp * 16 + dd2;
            ob[(size_t)d * HW] = cb[d * Kc + kf];
        }
    }
}

extern "C" void kernel_launch(void* const* d_in, const int* in_sizes, int n_in,
                              void* d_out, int out_size, void* d_ws, size_t ws_size,
                              hipStream_t stream) {
    const float* enc = (const float*)d_in[0];  // [32,64,64,64]
    const float* cb  = (const float*)d_in[1];  // [64,512]
    float* out = (float*)d_out;
    float* sqe = (float*)d_ws;                           // 512 f32
    float* maxsqe = (float*)((char*)d_ws + 2048);        // 1 f32
    unsigned short* cbT = (unsigned short*)((char*)d_ws + 4096);  // 64 KB

    vq_prep<<<1, 512, 0, stream>>>(cb, sqe, maxsqe, cbT);
    vq_mfma7<<<Np / POSB, 512, 0, stream>>>(enc, cb, sqe, maxsqe, cbT, out);
}

// Round 20
// 70.573 us; speedup vs baseline: 2.3086x; 2.3086x over previous
//
#include <hip/hip_runtime.h>
#include <hip/hip_bf16.h>

// VanillaVectorQuantizer: N=131072 pos (B=32,H=64,W=64), D=64, K=512.
// enc [B,D,H,W]: (b,d,p) at b*D*HW + d*HW + p.
//
// Architecture (r13-r18-proven, absmax==0): MFMA screen + GLOBAL-threshold
// bounded exact rescore. r20 = r18 (best known, 73.6us) + two safe
// micro-opts, after r19's wave-autonomous redesign regressed (163us:
// per-wave global B-reloads serialized on L2; barrier theory falsified):
//  (1) B-fragment + sqe loads HOISTED above staging (issue-early /
//      consume-late: they depend only on cbT/sqe, so their L2 latency
//      hides under staging's VALU+loads instead of following bar1).
//  (2) s_setprio(1) around MFMA clusters (phase-diverse co-resident
//      blocks -> scheduler arbitration favors the matrix-feeding wave).
//  screen: dd'_k = fl(sqe_k - 2*acc_k), acc = bf16 MFMA (fp32 accum).
//  bound:  B = 0.012*sqrt(sqx*maxsqe) + 3e-4  (r14-r18-verified).
//  capture: cand = {k: dd' <= gmin + 2B} -> true argmin + all exact ties.
//  n==1 fast path: unique candidate == provable argmin, no rescore.
//  rescore: EXACT numpy chain (bitwise, r2-r18): M ascending-d fp32 FMA;
//    sq_x pairwise tree; dist fl(fl(sqx-fl(2M))+sqe); u64 (distbits,k)
//    atomicMin == first-index tie-break. Overflow(>16) -> full 512 rescan.
// MFMA frags (r13-r18-verified): A = xbf[row*72 + s*32 + 8*hi];
// B = cbT[kg*64 + s*32 + 8*hi], kg = 64w + kt*16 + m; C/D row=4*hi+j, col=m.

#pragma clang fp contract(off)

#define D 64
#define Kc 512
#define HW 4096
#define Np 131072
#define POSB 128
#define NW 8
#define CAP 16

typedef __attribute__((ext_vector_type(8))) short bf16x8;
typedef __attribute__((ext_vector_type(4))) float f32x4;

static __device__ __forceinline__ unsigned short f2bf(float f) {
    __hip_bfloat16 h = __float2bfloat16(f);  // RN-even (bound covers it)
    return *reinterpret_cast<unsigned short*>(&h);
}
static __device__ __forceinline__ unsigned fmap(float f) {
    const unsigned u = __float_as_uint(f);
    return (u & 0x80000000u) ? ~u : (u | 0x80000000u);
}
static __device__ __forceinline__ float funmap(unsigned m) {
    const unsigned u = (m & 0x80000000u) ? (m & 0x7fffffffu) : ~m;
    return __uint_as_float(u);
}

// DPP value-move (VALU pipe; r18-HW-verified encodings).
template <int CTRL>
static __device__ __forceinline__ float dpp_mov(float x) {
    return __int_as_float(__builtin_amdgcn_update_dpp(
        __float_as_int(x), __float_as_int(x), CTRL, 0xF, 0xF, false));
}
static __device__ __forceinline__ float dpp_rowmin16(float x) {
    x = fminf(x, dpp_mov<0xB1>(x));   // quad_perm(1,0,3,2) == xor1
    x = fminf(x, dpp_mov<0x4E>(x));   // quad_perm(2,3,0,1) == xor2
    x = fminf(x, dpp_mov<0x124>(x));  // row_ror:4
    x = fminf(x, dpp_mov<0x128>(x));  // row_ror:8
    return x;  // all 16 lanes hold the row min
}

// Prep: exact sqe chain, max(sqe), cbT bf16 [512][64] (k-major).
__global__ __launch_bounds__(512) void vq_prep(
    const float* __restrict__ cb, float* __restrict__ sqe,
    float* __restrict__ maxsqe, unsigned short* __restrict__ cbT) {
    __shared__ float red[512];
    const int k = threadIdx.x;
    float s;
    unsigned pk[32];
    {
        const float v0 = cb[k], v1 = cb[Kc + k];
        s = v0 * v0;
        const float sq1 = v1 * v1;
        s = s + sq1;
        pk[0] = (unsigned)f2bf(v0) | ((unsigned)f2bf(v1) << 16);
    }
#pragma unroll
    for (int i = 1; i < 32; ++i) {
        const float v0 = cb[(2 * i) * Kc + k], v1 = cb[(2 * i + 1) * Kc + k];
        const float sq0 = v0 * v0;
        s = s + sq0;
        const float sq1 = v1 * v1;
        s = s + sq1;
        pk[i] = (unsigned)f2bf(v0) | ((unsigned)f2bf(v1) << 16);
    }
    sqe[k] = s;
    unsigned* crow = (unsigned*)(cbT + k * 64);
#pragma unroll
    for (int i = 0; i < 32; ++i) crow[i] = pk[i];
    red[k] = s;
    __syncthreads();
    for (int off = 256; off > 0; off >>= 1) {
        if (k < off) red[k] = fmaxf(red[k], red[k + off]);
        __syncthreads();
    }
    if (k == 0) maxsqe[0] = red[0];
}

__global__ __launch_bounds__(512) void vq_mfma8(
    const float* __restrict__ enc, const float* __restrict__ cb,
    const float* __restrict__ sqe, const float* __restrict__ maxsqe_p,
    const unsigned short* __restrict__ cbT, float* __restrict__ out) {
    __shared__ unsigned short xbf[POSB * 72];    // 18432 B, stride 144B
    __shared__ float sqx[POSB];                  //   512 B
    __shared__ float thrB[POSB];                 //   512 B (= 2*Bnd)
    __shared__ unsigned gminu[POSB];             //   512 B (mapped dd' min)
    __shared__ unsigned cnt[POSB];               //   512 B
    __shared__ unsigned short list[POSB * CAP];  //  4096 B
    __shared__ unsigned long long rmin[POSB];    //  1024 B (~25.6 KB)

    const int tid = threadIdx.x;
    const int w = tid >> 6;
    const int lane = tid & 63;
    const int m = lane & 15, hi = lane >> 4;
    const int p0 = blockIdx.x * POSB;  // 128 | 4096: block within one b
    const int b = p0 >> 12;
    const int r0 = p0 & (HW - 1);
    const float* eb = enc + (size_t)b * (D * HW) + r0;

    // ---- HOISTED (r20): B-fragments + sqe for this wave's k-range.
    // Depend only on cbT/sqe -> issue before staging; L2 latency hides
    // under the staging phase instead of following bar1. ----
    bf16x8 Bf[4][2];
    float se[4];
#pragma unroll
    for (int kt = 0; kt < 4; ++kt) {
        const int kg = 64 * w + kt * 16 + m;
#pragma unroll
        for (int s = 0; s < 2; ++s)
            Bf[kt][s] = *reinterpret_cast<const bf16x8*>(
                &cbT[kg * 64 + s * 32 + 8 * hi]);
        se[kt] = sqe[kg];
    }

    // ---- Stage (r16-r18-verified): thread owns (p = tid>>2, h = tid&3):
    // stride-8 pairwise accumulators; quad-DPP tree completes sx bitwise. ----
    {
        const int p = tid >> 2, h = tid & 3;
        const float* ebp = eb + p;
        float pa, pb2;
        {
            const int d = 2 * h;
            const float v0 = ebp[(size_t)d * HW], v1 = ebp[(size_t)(d + 1) * HW];
            pa = v0 * v0;
            pb2 = v1 * v1;
            *reinterpret_cast<unsigned*>(
                reinterpret_cast<char*>(xbf) + p * 144 + 4 * h) =
                (unsigned)f2bf(v0) | ((unsigned)f2bf(v1) << 16);
        }
#pragma unroll
        for (int i = 1; i < 8; ++i) {
            const int d = 8 * i + 2 * h;
            const float v0 = ebp[(size_t)d * HW], v1 = ebp[(size_t)(d + 1) * HW];
            const float s0 = v0 * v0;  // rounded square
            pa = pa + s0;              // rounded add (stride-8 acc 2h)
            const float s1 = v1 * v1;
            pb2 = pb2 + s1;            // (stride-8 acc 2h+1)
            *reinterpret_cast<unsigned*>(
                reinterpret_cast<char*>(xbf) + p * 144 + 16 * i + 4 * h) =
                (unsigned)f2bf(v0) | ((unsigned)f2bf(v1) << 16);
        }
        const float node = pa + pb2;             // n_h
        const float o1 = dpp_mov<0xB1>(node);    // lane^1 partner
        const float t = node + o1;               // n0+n1 / n2+n3
        const float o2 = dpp_mov<0x4E>(t);       // lane^2 partner
        const float sx = t + o2;                 // full tree
        if (h == 0) {
            sqx[p] = sx;
            thrB[p] = 2.0f * (0.012f * sqrtf(sx * maxsqe_p[0]) + 3e-4f);
        }
    }
    if (tid < POSB) {
        cnt[tid] = 0;
        rmin[tid] = ~0ULL;
        gminu[tid] = 0xFFFFFFFFu;
    }
    __syncthreads();  // bar1

    // ---- Pass 1: row-min of dd' -> DPP row-reduce -> LDS atomicMin ----
#pragma unroll 2
    for (int pt = 0; pt < POSB / 16; ++pt) {
        const int rowb = pt * 16;
        f32x4 acc[4] = {};
        {
            const bf16x8 A0 = *reinterpret_cast<const bf16x8*>(
                &xbf[(rowb + m) * 72 + 8 * hi]);
            __builtin_amdgcn_s_setprio(1);
#pragma unroll
            for (int kt = 0; kt < 4; ++kt)
                acc[kt] = __builtin_amdgcn_mfma_f32_16x16x32_bf16(
                    A0, Bf[kt][0], acc[kt], 0, 0, 0);
            __builtin_amdgcn_s_setprio(0);
            const bf16x8 A1 = *reinterpret_cast<const bf16x8*>(
                &xbf[(rowb + m) * 72 + 32 + 8 * hi]);
            __builtin_amdgcn_s_setprio(1);
#pragma unroll
            for (int kt = 0; kt < 4; ++kt)
                acc[kt] = __builtin_amdgcn_mfma_f32_16x16x32_bf16(
                    A1, Bf[kt][1], acc[kt], 0, 0, 0);
            __builtin_amdgcn_s_setprio(0);
        }
        float mn0 = 3.4e38f, mn1 = 3.4e38f, mn2 = 3.4e38f, mn3 = 3.4e38f;
#pragma unroll
        for (int kt = 0; kt < 4; ++kt) {
            mn0 = fminf(mn0, fmaf(-2.f, acc[kt][0], se[kt]));
            mn1 = fminf(mn1, fmaf(-2.f, acc[kt][1], se[kt]));
            mn2 = fminf(mn2, fmaf(-2.f, acc[kt][2], se[kt]));
            mn3 = fminf(mn3, fmaf(-2.f, acc[kt][3], se[kt]));
        }
        mn0 = dpp_rowmin16(mn0);
        mn1 = dpp_rowmin16(mn1);
        mn2 = dpp_rowmin16(mn2);
        mn3 = dpp_rowmin16(mn3);
        if (m == 0) {
            atomicMin(&gminu[rowb + 4 * hi + 0], fmap(mn0));
            atomicMin(&gminu[rowb + 4 * hi + 1], fmap(mn1));
            atomicMin(&gminu[rowb + 4 * hi + 2], fmap(mn2));
            atomicMin(&gminu[rowb + 4 * hi + 3], fmap(mn3));
        }
    }
    __syncthreads();  // bar2 (gmin complete)

    // ---- Pass 2: collect candidates vs global window ----
#pragma unroll 2
    for (int pt = 0; pt < POSB / 16; ++pt) {
        const int rowb = pt * 16;
        f32x4 acc[4] = {};
        {
            const bf16x8 A0 = *reinterpret_cast<const bf16x8*>(
                &xbf[(rowb + m) * 72 + 8 * hi]);
            __builtin_amdgcn_s_setprio(1);
#pragma unroll
            for (int kt = 0; kt < 4; ++kt)
                acc[kt] = __builtin_amdgcn_mfma_f32_16x16x32_bf16(
                    A0, Bf[kt][0], acc[kt], 0, 0, 0);
            __builtin_amdgcn_s_setprio(0);
            const bf16x8 A1 = *reinterpret_cast<const bf16x8*>(
                &xbf[(rowb + m) * 72 + 32 + 8 * hi]);
            __builtin_amdgcn_s_setprio(1);
#pragma unroll
            for (int kt = 0; kt < 4; ++kt)
                acc[kt] = __builtin_amdgcn_mfma_f32_16x16x32_bf16(
                    A1, Bf[kt][1], acc[kt], 0, 0, 0);
            __builtin_amdgcn_s_setprio(0);
        }
        const float4 tb = *reinterpret_cast<const float4*>(&thrB[rowb + 4 * hi]);
        const uint4 gm = *reinterpret_cast<const uint4*>(&gminu[rowb + 4 * hi]);
        const float win0 = funmap(gm.x) + tb.x;
        const float win1 = funmap(gm.y) + tb.y;
        const float win2 = funmap(gm.z) + tb.z;
        const float win3 = funmap(gm.w) + tb.w;
#pragma unroll
        for (int kt = 0; kt < 4; ++kt) {
            const unsigned kg = 64 * w + kt * 16 + m;
            const float dd0 = fmaf(-2.f, acc[kt][0], se[kt]);
            const float dd1 = fmaf(-2.f, acc[kt][1], se[kt]);
            const float dd2 = fmaf(-2.f, acc[kt][2], se[kt]);
            const float dd3 = fmaf(-2.f, acc[kt][3], se[kt]);
            if (dd0 <= win0) {
                const unsigned idx = atomicAdd(&cnt[rowb + 4 * hi + 0], 1u);
                if (idx < CAP) list[(rowb + 4 * hi + 0) * CAP + idx] = (unsigned short)kg;
            }
            if (dd1 <= win1) {
                const unsigned idx = atomicAdd(&cnt[rowb + 4 * hi + 1], 1u);
                if (idx < CAP) list[(rowb + 4 * hi + 1) * CAP + idx] = (unsigned short)kg;
            }
            if (dd2 <= win2) {
                const unsigned idx = atomicAdd(&cnt[rowb + 4 * hi + 2], 1u);
                if (idx < CAP) list[(rowb + 4 * hi + 2) * CAP + idx] = (unsigned short)kg;
            }
            if (dd3 <= win3) {
                const unsigned idx = atomicAdd(&cnt[rowb + 4 * hi + 3], 1u);
                if (idx < CAP) list[(rowb + 4 * hi + 3) * CAP + idx] = (unsigned short)kg;
            }
        }
    }
    __syncthreads();  // bar3 (lists done)

    // ---- Exact rescore; n==1 fast path (no chain needed) ----
    {
        const int p = tid >> 2, sub = tid & 3;
        const unsigned n = cnt[p];
        if (n == 1) {
            if (sub == 0) rmin[p] = (unsigned long long)list[p * CAP];
        } else if (n <= CAP) {
            const float sx = sqx[p];
            unsigned long long mloc = ~0ULL;
            for (unsigned c = sub; c < n; c += 4) {
                const int k = list[p * CAP + c];
                float M = 0.f;
#pragma unroll 8
                for (int d = 0; d < D; ++d)
                    M = fmaf(eb[(size_t)d * HW + p], cb[d * Kc + k], M);
                const float m2 = 2.0f * M;
                const float tmp = sx - m2;
                const float dd = tmp + sqe[k];
                const unsigned long long pk =
                    ((unsigned long long)__float_as_uint(dd) << 32) | (unsigned)k;
                if (pk < mloc) mloc = pk;
            }
            if (mloc != ~0ULL) atomicMin(&rmin[p], mloc);
        } else {  // overflow: full exact rescan (practically never; airtight)
            const float sx = sqx[p];
            unsigned long long mloc = ~0ULL;
            for (unsigned k = sub; k < (unsigned)Kc; k += 4) {
                float M = 0.f;
#pragma unroll 8
                for (int d = 0; d < D; ++d)
                    M = fmaf(eb[(size_t)d * HW + p], cb[d * Kc + k], M);
                const float m2 = 2.0f * M;
                const float tmp = sx - m2;
                const float dd = tmp + sqe[k];
                const unsigned long long pk =
                    ((unsigned long long)__float_as_uint(dd) << 32) | k;
                if (pk < mloc) mloc = pk;
            }
            atomicMin(&rmin[p], mloc);
        }
    }
    __syncthreads();  // bar4

    // ---- Output: thread (d = tid>>3, pg = tid&7), 2 reps of 8 pos ----
    {
        const int d = tid >> 3, pg = tid & 7;
        float* ob = out + (size_t)b * (D * HW) + r0 + (size_t)d * HW;
#pragma unroll
        for (int r = 0; r < 2; ++r) {
            const int pb = r * 64 + pg * 8;
            float o[8];
#pragma unroll
            for (int i = 0; i < 8; ++i) {
                const int k = (int)(rmin[pb + i] & 0xffffffffu);
                o[i] = cb[d * Kc + k];
            }
            float4 v0 = {o[0], o[1], o[2], o[3]};
            float4 v1 = {o[4], o[5], o[6], o[7]};
            *reinterpret_cast<float4*>(ob + pb) = v0;
            *reinterpret_cast<float4*>(ob + pb + 4) = v1;
        }
    }
}

extern "C" void kernel_launch(void* const* d_in, const int* in_sizes, int n_in,
                              void* d_out, int out_size, void* d_ws, size_t ws_size,
                              hipStream_t stream) {
    const float* enc = (const float*)d_in[0];  // [32,64,64,64]
    const float* cb  = (const float*)d_in[1];  // [64,512]
    float* out = (float*)d_out;
    float* sqe = (float*)d_ws;                           // 512 f32
    float* maxsqe = (float*)((char*)d_ws + 2048);        // 1 f32
    unsigned short* cbT = (unsigned short*)((char*)d_ws + 4096);  // 64 KB

    vq_prep<<<1, 512, 0, stream>>>(cb, sqe, maxsqe, cbT);
    vq_mfma8<<<Np / POSB, 512, 0, stream>>>(enc, cb, sqe, maxsqe, cbT, out);
}